// Round 8
// baseline (460.821 us; speedup 1.0000x reference)
//
#include <hip/hip_runtime.h>
#include <cstdint>
#include <cstddef>

#define D_MODEL 2048
#define NHEAD 16
#define HEAD_DIM 128
#define BATCH 4
#define SEQ 2048
#define MROWS (BATCH * SEQ)   // 8192
#define LN_EPS 1e-5f

typedef __bf16 bf16x8 __attribute__((ext_vector_type(8)));
typedef float f32x4 __attribute__((ext_vector_type(4)));
typedef unsigned short u16x8 __attribute__((ext_vector_type(8)));

static __device__ __forceinline__ unsigned short f2bf(float f) {
    unsigned u = __float_as_uint(f);
    u += 0x7FFFu + ((u >> 16) & 1u);          // round-to-nearest-even
    return (unsigned short)(u >> 16);
}
static __device__ __forceinline__ float bf2f(unsigned short h) {
    return __uint_as_float(((unsigned)h) << 16);
}

// async global->LDS, 16 B per lane. LDS dest is wave-uniform base + lane*16.
typedef __attribute__((address_space(1))) const unsigned int gu32_t;
typedef __attribute__((address_space(3))) unsigned int lu32_t;
static __device__ __forceinline__ void load_lds16(const unsigned short* g,
                                                  unsigned short* l) {
    __builtin_amdgcn_global_load_lds((gu32_t*)g, (lu32_t*)l, 16, 0, 0);
}

// ---------------- cast fp32 -> bf16 ----------------
__global__ void cast_kernel(const float* __restrict__ in,
                            unsigned short* __restrict__ out, int n) {
    int i = (blockIdx.x * blockDim.x + threadIdx.x) * 4;
    if (i >= n) return;
    float4 f = *(const float4*)(in + i);
    ushort4 o;
    o.x = f2bf(f.x); o.y = f2bf(f.y); o.z = f2bf(f.z); o.w = f2bf(f.w);
    *(ushort4*)(out + i) = o;
}

// one dispatch for all 4 weight matrices (outputs are contiguous in ws)
__global__ void cast4_kernel(const float* __restrict__ w0, const float* __restrict__ w1,
                             const float* __restrict__ w2, const float* __restrict__ w3,
                             unsigned short* __restrict__ out) {
    const long SZW = (long)D_MODEL * D_MODEL;            // 4.2M, 4096 blocks/mat
    int m = blockIdx.x >> 12;
    long i = ((long)(blockIdx.x & 4095) * 256 + threadIdx.x) * 4;
    const float* w = (m == 0) ? w0 : (m == 1) ? w1 : (m == 2) ? w2 : w3;
    float4 f = *(const float4*)(w + i);
    ushort4 o;
    o.x = f2bf(f.x); o.y = f2bf(f.y); o.z = f2bf(f.z); o.w = f2bf(f.w);
    *(ushort4*)(out + m * SZW + i) = o;
}

// ---------------- bf16 GEMM:  C[M,N] = A[M,K] @ B[N,K]^T ----------------
// 256x256 tile, BK=64, 512 threads (8 waves, 2x4).  v4: faithful m201-style
// quadrant schedule.  Key structural features (absent from v1-v3):
//  - Fragment layout splits each wave's output across TILE halves:
//      A rows: (i>>2)*128 + wr*64 + (i&3)*16   (i<4 -> half0, i>=4 -> half1)
//      B cols: (j>>1)*128 + wc*32 + (j&1)*16   (j<2 -> half0, j>=2 -> half1)
//    so each phase = one C-quadrant Q(ih,jh) whose ds_reads are exactly its
//    MFMA operands (consumed in-phase -> LDS half-regions free early).
//  - Quadrant order Q00,Q10,Q01,Q11; per phase: {reads; stage 1 half-tile;
//    BAR; lgkm(0)+sched_barrier; setprio(1); 16 MFMA; setprio(0); BAR}.
//  - Uniform staging, 1 half-tile/phase:  ph0: Ah1(X+1)  ph1: Bh1(X+1)
//    ph2: Bh0(X+2)  ph3: Ah0(X+2).  Every half-tile lands in a region whose
//    last ds_read completed >=2 barriers earlier (WAR-safe), and is >=5
//    phases old at first read (RAW-safe).
//  - ONE vmcnt(4) per K-tile at the boundary (leaves the 2 newest half-tiles
//    in flight); vmcnt(0) only on the last two K-tiles (tail).
// No XCD swizzle: R7 measured it DOUBLES FETCH (176->320 MB) — the default
// round-robin already pins 3 B-panels per XCD (24 % 8 == 0).
#define BAR() asm volatile("s_barrier" ::: "memory")
#define MIDSYNC() do { BAR(); \
    asm volatile("s_waitcnt lgkmcnt(0)" ::: "memory"); \
    __builtin_amdgcn_sched_barrier(0); } while (0)

template<int OUT_BF16>
__global__ __launch_bounds__(512, 2) void gemm256(const unsigned short* __restrict__ A,
                                                  const unsigned short* __restrict__ Bbase,
                                                  void* __restrict__ Cv,
                                                  int M, int N, int K, int ntiles)
{
    __shared__ __align__(16) unsigned short As[2][16384];   // [buf][half 8192]
    __shared__ __align__(16) unsigned short Bs[2][16384];
    const int tid  = threadIdx.x;
    const int wave = tid >> 6, lane = tid & 63;
    const int r = lane & 15, q4 = lane >> 4;
    const int wr = wave >> 2, wc = wave & 3;      // 2x4 wave grid
    const int mat = blockIdx.x / ntiles;
    const int xt  = blockIdx.x % ntiles;
    const int bm  = (int)blockIdx.y << 8;
    const int bn  = xt << 8;
    const unsigned short* B = Bbase + (long)mat * N * (long)K;

    // staging source byte-offsets: lane writes LDS-linear off; global source
    // is inverse-swizzled so LDS[row][cb] = G[row][cb ^ ((row&7)<<4)].
    int offA[2][2], offB[2][2];
#pragma unroll
    for (int h = 0; h < 2; ++h)
#pragma unroll
        for (int i = 0; i < 2; ++i) {
            int off  = h * 16384 + i * 8192 + wave * 1024 + (lane << 4);
            int row  = off >> 7;                         // 0..255 (tile row)
            int colb = (off & 127) ^ ((row & 7) << 4);   // swizzled col byte
            offA[h][i] = (bm + row) * (K * 2) + colb;
            offB[h][i] = (bn + row) * (K * 2) + colb;
        }
    // swizzled ds_read col offsets (elements) for kstep 0/1
    const int xr  = (r & 7) << 4;
    const int cs0 = ((q4 * 16) ^ xr) >> 1;
    const int cs1 = ((64 + q4 * 16) ^ xr) >> 1;

    f32x4 acc[8][4];
#pragma unroll
    for (int i = 0; i < 8; ++i)
#pragma unroll
        for (int j = 0; j < 4; ++j) acc[i][j] = (f32x4){0.f, 0.f, 0.f, 0.f};

    const char* Ac = (const char*)A;
    const char* Bc = (const char*)B;
    auto stA = [&](int buf, int h, int kt) {     // stage A half-tile h of K-tile kt
        load_lds16((const unsigned short*)(Ac + offA[h][0] + kt * 128),
                   &As[buf][h * 8192 + wave * 512]);
        load_lds16((const unsigned short*)(Ac + offA[h][1] + kt * 128),
                   &As[buf][h * 8192 + 4096 + wave * 512]);
    };
    auto stB = [&](int buf, int h, int kt) {
        load_lds16((const unsigned short*)(Bc + offB[h][0] + kt * 128),
                   &Bs[buf][h * 8192 + wave * 512]);
        load_lds16((const unsigned short*)(Bc + offB[h][1] + kt * 128),
                   &Bs[buf][h * 8192 + 4096 + wave * 512]);
    };
    // quadrant reads: A half ih -> 4 frags x 2 ksteps; B half jh -> 2 x 2
    auto rdAh = [&](const unsigned short* Ab, int ih, bf16x8 dst[4][2]) {
#pragma unroll
        for (int m = 0; m < 4; ++m) {
            int rowh = wr * 64 + m * 16 + r;
            dst[m][0] = *(const bf16x8*)&Ab[ih * 8192 + rowh * 64 + cs0];
            dst[m][1] = *(const bf16x8*)&Ab[ih * 8192 + rowh * 64 + cs1];
        }
    };
    auto rdBh = [&](const unsigned short* Bb, int jh, bf16x8 dst[2][2]) {
#pragma unroll
        for (int n = 0; n < 2; ++n) {
            int rowh = wc * 32 + n * 16 + r;
            dst[n][0] = *(const bf16x8*)&Bb[jh * 8192 + rowh * 64 + cs0];
            dst[n][1] = *(const bf16x8*)&Bb[jh * 8192 + rowh * 64 + cs1];
        }
    };

    const int nt = K >> 6;
    // prologue: tile0 fully (8 loads) + Bh0(1), Ah0(1) (4 loads).
    // vmcnt(4) drains tile0, leaves tile1's first 2 half-tiles in flight.
    stA(0, 0, 0); stA(0, 1, 0);
    stB(0, 0, 0); stB(0, 1, 0);
    if (nt > 1) {
        stB(1, 0, 1); stA(1, 0, 1);
        asm volatile("s_waitcnt vmcnt(4)" ::: "memory");
    } else {
        asm volatile("s_waitcnt vmcnt(0)" ::: "memory");
    }
    BAR();

    for (int X = 0; X < nt; ++X) {
        const int x = X & 1;
        const unsigned short* Ab = As[x];
        const unsigned short* Bb = Bs[x];
        const bool p1 = (X + 1 < nt), p2 = (X + 2 < nt);
        bf16x8 a0[4][2], a1[4][2], b0[2][2], b1[2][2];

        // ---- ph0: Q(0,0)  reads Ah0+Bh0 (12); stage Ah1(X+1) ----
        rdAh(Ab, 0, a0);
        rdBh(Bb, 0, b0);
        if (p1) stA(x ^ 1, 1, X + 1);
        MIDSYNC();
        __builtin_amdgcn_s_setprio(1);
#pragma unroll
        for (int ks = 0; ks < 2; ++ks)
#pragma unroll
            for (int m = 0; m < 4; ++m)
#pragma unroll
                for (int n = 0; n < 2; ++n)
                    acc[m][n] = __builtin_amdgcn_mfma_f32_16x16x32_bf16(
                        a0[m][ks], b0[n][ks], acc[m][n], 0, 0, 0);
        __builtin_amdgcn_s_setprio(0);
        BAR();

        // ---- ph1: Q(1,0)  reads Ah1 (8); stage Bh1(X+1) ----
        rdAh(Ab, 1, a1);
        if (p1) stB(x ^ 1, 1, X + 1);
        MIDSYNC();
        __builtin_amdgcn_s_setprio(1);
#pragma unroll
        for (int ks = 0; ks < 2; ++ks)
#pragma unroll
            for (int m = 0; m < 4; ++m)
#pragma unroll
                for (int n = 0; n < 2; ++n)
                    acc[4 + m][n] = __builtin_amdgcn_mfma_f32_16x16x32_bf16(
                        a1[m][ks], b0[n][ks], acc[4 + m][n], 0, 0, 0);
        __builtin_amdgcn_s_setprio(0);
        BAR();

        // ---- ph2: Q(0,1)  reads Bh1 (4); stage Bh0(X+2) ----
        rdBh(Bb, 1, b1);
        if (p2) stB(x, 0, X + 2);
        MIDSYNC();
        __builtin_amdgcn_s_setprio(1);
#pragma unroll
        for (int ks = 0; ks < 2; ++ks)
#pragma unroll
            for (int m = 0; m < 4; ++m)
#pragma unroll
                for (int n = 0; n < 2; ++n)
                    acc[m][2 + n] = __builtin_amdgcn_mfma_f32_16x16x32_bf16(
                        a0[m][ks], b1[n][ks], acc[m][2 + n], 0, 0, 0);
        __builtin_amdgcn_s_setprio(0);
        BAR();

        // ---- ph3: Q(1,1)  no reads; stage Ah0(X+2); boundary ----
        if (p2) stA(x, 0, X + 2);
        BAR();
        __builtin_amdgcn_s_setprio(1);
#pragma unroll
        for (int ks = 0; ks < 2; ++ks)
#pragma unroll
            for (int m = 0; m < 4; ++m)
#pragma unroll
                for (int n = 0; n < 2; ++n)
                    acc[4 + m][2 + n] = __builtin_amdgcn_mfma_f32_16x16x32_bf16(
                        a1[m][ks], b1[n][ks], acc[4 + m][2 + n], 0, 0, 0);
        __builtin_amdgcn_s_setprio(0);
        if (p2)                  // counted: 2 newest half-tiles stay in flight
            asm volatile("s_waitcnt vmcnt(4)" ::: "memory");
        else                     // tail (last 2 K-tiles): full drain
            asm volatile("s_waitcnt vmcnt(0)" ::: "memory");
        BAR();
    }

    // epilogue: frag (i,j) -> row = (i>>2)*128 + wr*64 + (i&3)*16 + q4*4 + e,
    //                         col = (j>>1)*128 + wc*32 + (j&1)*16 + r
    const long cmat = (long)mat * M * (long)N;
#pragma unroll
    for (int i = 0; i < 8; ++i) {
#pragma unroll
        for (int j = 0; j < 4; ++j) {
            long row = bm + (i >> 2) * 128 + wr * 64 + (i & 3) * 16 + q4 * 4;
            long col = bn + (j >> 1) * 128 + wc * 32 + (j & 1) * 16 + r;
#pragma unroll
            for (int e = 0; e < 4; ++e) {
                float val = acc[i][j][e];
                if (OUT_BF16)
                    ((unsigned short*)Cv)[cmat + (row + e) * (long)N + col] = f2bf(val);
                else
                    ((float*)Cv)[cmat + (row + e) * (long)N + col] = val;
            }
        }
    }
}

// ---------------- FUSED decay recurrence + q*state + LayerNorm + SiLU gate --
// Block = (batch b, 32-token chunk c); 256 threads; thread owns 8 CONTIGUOUS
// d-columns (head h = tid>>4).  Warm-up 64 steps (exact to fp32), 32 live
// steps; all global access 16B/lane contiguous; y staged in 128KB LDS tile;
// LN + silu(gate) -> y2 directly.
#define FCHUNK 32
#define FWARM 64
__global__ __launch_bounds__(256) void retn_ln_kernel(
    const unsigned short* __restrict__ qb,
    const unsigned short* __restrict__ vb,
    const unsigned short* __restrict__ gb,
    const float* __restrict__ beta,
    const float* __restrict__ ln_w,
    const float* __restrict__ ln_b,
    unsigned short* __restrict__ y2)
{
    __shared__ __align__(16) unsigned short y_lds[FCHUNK][D_MODEL];  // 128 KB
    __shared__ float ssum[4][8][4], ssq[4][8][4];
    const int tid  = threadIdx.x;
    const int wid  = tid >> 6, lane = tid & 63;
    const int b    = blockIdx.x >> 6;          // SEQ/FCHUNK = 64 chunks
    const int c    = blockIdx.x & 63;
    const int s0   = c * FCHUNK;
    const int e0   = tid * 8;                  // this thread's 8 columns
    const int h    = tid >> 4;                 // e0/HEAD_DIM
    const float lam = 1.f / (1.f + expf(-beta[h]));
    const long rowbase = (long)b * SEQ;

    float st[8];
#pragma unroll
    for (int i = 0; i < 8; ++i) st[i] = 0.f;

    int sw = s0 - FWARM; if (sw < 0) sw = 0;   // (s0-sw) in {0,32,64}
    for (int s = sw; s < s0; s += 8) {
        u16x8 vv[8];
#pragma unroll
        for (int k = 0; k < 8; ++k)
            vv[k] = *(const u16x8*)&vb[(rowbase + s + k) * D_MODEL + e0];
#pragma unroll
        for (int k = 0; k < 8; ++k)
#pragma unroll
            for (int i = 0; i < 8; ++i) st[i] = lam * st[i] + bf2f(vv[k][i]);
    }
    for (int ls = 0; ls < FCHUNK; ls += 8) {
        u16x8 vv[8], qq[8];
#pragma unroll
        for (int k = 0; k < 8; ++k)
            vv[k] = *(const u16x8*)&vb[(rowbase + s0 + ls + k) * D_MODEL + e0];
#pragma unroll
        for (int k = 0; k < 8; ++k)
            qq[k] = *(const u16x8*)&qb[(rowbase + s0 + ls + k) * D_MODEL + e0];
#pragma unroll
        for (int k = 0; k < 8; ++k) {
            u16x8 o;
#pragma unroll
            for (int i = 0; i < 8; ++i) {
                st[i] = lam * st[i] + bf2f(vv[k][i]);
                o[i]  = f2bf(bf2f(qq[k][i]) * st[i]);
            }
            *(u16x8*)&y_lds[ls + k][e0] = o;
        }
    }
    __syncthreads();

    float lw[8], lb[8];
    {
        float4 a0 = *(const float4*)&ln_w[e0];
        float4 a1 = *(const float4*)&ln_w[e0 + 4];
        float4 b0 = *(const float4*)&ln_b[e0];
        float4 b1 = *(const float4*)&ln_b[e0 + 4];
        lw[0]=a0.x; lw[1]=a0.y; lw[2]=a0.z; lw[3]=a0.w;
        lw[4]=a1.x; lw[5]=a1.y; lw[6]=a1.z; lw[7]=a1.w;
        lb[0]=b0.x; lb[1]=b0.y; lb[2]=b0.z; lb[3]=b0.w;
        lb[4]=b1.x; lb[5]=b1.y; lb[6]=b1.z; lb[7]=b1.w;
    }

    for (int g = 0; g < 4; ++g) {
        u16x8 gv[8], yv[8];
#pragma unroll
        for (int tt = 0; tt < 8; ++tt)       // prefetch gates early
            gv[tt] = *(const u16x8*)&gb[(rowbase + s0 + g * 8 + tt) * D_MODEL + e0];
        float psum[8], psq[8];
#pragma unroll
        for (int tt = 0; tt < 8; ++tt) {
            yv[tt] = *(const u16x8*)&y_lds[g * 8 + tt][e0];
            float su = 0.f, sq = 0.f;
#pragma unroll
            for (int i = 0; i < 8; ++i) { float f = bf2f(yv[tt][i]); su += f; sq += f * f; }
            psum[tt] = su; psq[tt] = sq;
        }
#pragma unroll
        for (int off = 32; off > 0; off >>= 1)
#pragma unroll
            for (int tt = 0; tt < 8; ++tt) {
                psum[tt] += __shfl_down(psum[tt], off);
                psq[tt]  += __shfl_down(psq[tt],  off);
            }
        if (lane == 0)
#pragma unroll
            for (int tt = 0; tt < 8; ++tt) { ssum[g][tt][wid] = psum[tt]; ssq[g][tt][wid] = psq[tt]; }
        __syncthreads();
#pragma unroll
        for (int tt = 0; tt < 8; ++tt) {
            float sum = ssum[g][tt][0] + ssum[g][tt][1] + ssum[g][tt][2] + ssum[g][tt][3];
            float sq  = ssq[g][tt][0]  + ssq[g][tt][1]  + ssq[g][tt][2]  + ssq[g][tt][3];
            float mu  = sum * (1.f / D_MODEL);
            float var = sq * (1.f / D_MODEL) - mu * mu;
            float rs  = rsqrtf(var + LN_EPS);
            u16x8 ov;
#pragma unroll
            for (int i = 0; i < 8; ++i) {
                float gf   = bf2f(gv[tt][i]);
                float gate = gf / (1.f + expf(-gf));       // silu
                float yvf  = (bf2f(yv[tt][i]) - mu) * rs * lw[i] + lb[i];
                ov[i] = f2bf(yvf * gate);
            }
            *(u16x8*)&y2[(rowbase + s0 + g * 8 + tt) * D_MODEL + e0] = ov;
        }
    }
}

extern "C" void kernel_launch(void* const* d_in, const int* in_sizes, int n_in,
                              void* d_out, int out_size, void* d_ws, size_t ws_size,
                              hipStream_t stream)
{
    (void)in_sizes; (void)n_in; (void)out_size; (void)ws_size;
    const float* x    = (const float*)d_in[0];
    const float* Wq   = (const float*)d_in[1];
    const float* Wv   = (const float*)d_in[2];
    const float* Wg   = (const float*)d_in[3];
    const float* Wo   = (const float*)d_in[4];
    const float* beta = (const float*)d_in[5];
    const float* lnw  = (const float*)d_in[6];
    const float* lnb  = (const float*)d_in[7];

    const long SZX = (long)MROWS * D_MODEL;    // 16.8M
    const long SZW = (long)D_MODEL * D_MODEL;  // 4.2M

    unsigned short* ws  = (unsigned short*)d_ws;
    unsigned short* xb  = ws;            // SZX, reused as y2 after LN
    unsigned short* wqb = xb + SZX;      // SZW, fused B matrix 0
    unsigned short* wvb = wqb + SZW;     // SZW, fused B matrix 1
    unsigned short* wgb = wvb + SZW;     // SZW, fused B matrix 2
    unsigned short* wob = wgb + SZW;     // SZW
    unsigned short* qb  = wob + SZW;     // SZX, fused C tensor 0
    unsigned short* vb  = qb + SZX;      // SZX, fused C tensor 1
    unsigned short* gb  = vb + SZX;      // SZX, fused C tensor 2

    cast_kernel<<<(int)(SZX / 1024), 256, 0, stream>>>(x, xb, (int)SZX);
    cast4_kernel<<<4 * (int)(SZW / 1024), 256, 0, stream>>>(Wq, Wv, Wg, Wo, wqb);

    // fused Q/V/G projection: 3 B-matrices, 3 C-tensors, one dispatch
    dim3 gridQVG(3 * (D_MODEL / 256), MROWS / 256);   // 24 x 32
    gemm256<1><<<gridQVG, 512, 0, stream>>>(xb, wqb, qb,
                                            MROWS, D_MODEL, D_MODEL, D_MODEL / 256);

    // fused recurrence + LN + gate (writes y2 = xb directly; no tb buffer)
    retn_ln_kernel<<<BATCH * (SEQ / FCHUNK), 256, 0, stream>>>(qb, vb, gb,
                                                               beta, lnw, lnb, xb);

    dim3 gridO(D_MODEL / 256, MROWS / 256);           // 8 x 32
    gemm256<0><<<gridO, 512, 0, stream>>>(xb, wob, d_out,
                                          MROWS, D_MODEL, D_MODEL, D_MODEL / 256);
}